// Round 5
// baseline (1651.454 us; speedup 1.0000x reference)
//
#include <hip/hip_runtime.h>
#include <cstddef>

#define NUM_INST 32
#define EPS_IN 1e-5f

__device__ __forceinline__ int reflect_idx(int i, int n) {
    if (i < 0) i = -i;
    else if (i >= n) i = 2 * n - 2 - i;
    return i;
}

// ---------------- 7x7 reflect-pad conv, LDS-staged ---------------------------
template<int CIN, int COUT, int NCH, bool NORM, bool TANH>
__global__ void __launch_bounds__(256, 4)
conv7_lds(const float* __restrict__ x, const float* __restrict__ w,
          const float* __restrict__ bias,
          const float* __restrict__ mu, const float* __restrict__ rs,
          float* __restrict__ y, int H, int W)
{
    constexpr int COUTP = (COUT + 3) & ~3;
    __shared__ float wsm[CIN * 49 * COUTP];    // [ic][kh][kw][ocp]
    __shared__ float tile[NCH][38 * 39];
    __shared__ float smu[CIN], srs[CIN];
    const int tid = threadIdx.x;
    const int b = blockIdx.z;

    for (int idx = tid; idx < CIN * 49 * COUTP; idx += 256) {
        int ocp = idx % COUTP;
        int r   = idx / COUTP;
        wsm[idx] = (ocp < COUT) ? w[(size_t)ocp * CIN * 49 + r] : 0.f;
    }
    if (NORM && tid < CIN) { smu[tid] = mu[b * CIN + tid]; srs[tid] = rs[b * CIN + tid]; }

    const int oh_base = blockIdx.y * 32, ow_base = blockIdx.x * 32;
    const int ohl = tid >> 3, owl0 = (tid & 7) * 4;

    float acc[4][COUT];
#pragma unroll
    for (int o = 0; o < COUT; ++o) {
        float bv = bias[o];
#pragma unroll
        for (int j = 0; j < 4; ++j) acc[j][o] = bv;
    }

    for (int ic0 = 0; ic0 < CIN; ic0 += NCH) {
        __syncthreads();
        for (int idx = tid; idx < NCH * 1444; idx += 256) {
            int c = idx / 1444;
            int rr = idx % 1444;
            int r = rr / 38, col = rr % 38;
            int gy = reflect_idx(oh_base - 3 + r, H);
            int gx = reflect_idx(ow_base - 3 + col, W);
            float v = x[((size_t)(b * CIN + ic0 + c)) * H * W + (size_t)gy * W + gx];
            if (NORM) v = fmaxf((v - smu[ic0 + c]) * srs[ic0 + c], 0.f);
            tile[c][r * 39 + col] = v;
        }
        __syncthreads();
#pragma unroll
        for (int cc = 0; cc < NCH; ++cc) {
            const float* tp = &tile[cc][0];
            const float4* wp4 = (const float4*)&wsm[(ic0 + cc) * 49 * COUTP];
#pragma unroll
            for (int kh = 0; kh < 7; ++kh) {
                float rv[10];
#pragma unroll
                for (int i = 0; i < 10; ++i) rv[i] = tp[(ohl + kh) * 39 + owl0 + i];
#pragma unroll
                for (int kw = 0; kw < 7; ++kw) {
#pragma unroll
                    for (int o4 = 0; o4 < COUTP / 4; ++o4) {
                        float4 wv = wp4[(kh * 7 + kw) * (COUTP / 4) + o4];
#pragma unroll
                        for (int j = 0; j < 4; ++j) {
                            if (o4 * 4 + 0 < COUT) acc[j][o4 * 4 + 0] += rv[kw + j] * wv.x;
                            if (o4 * 4 + 1 < COUT) acc[j][o4 * 4 + 1] += rv[kw + j] * wv.y;
                            if (o4 * 4 + 2 < COUT) acc[j][o4 * 4 + 2] += rv[kw + j] * wv.z;
                            if (o4 * 4 + 3 < COUT) acc[j][o4 * 4 + 3] += rv[kw + j] * wv.w;
                        }
                    }
                }
            }
        }
    }

    const int oh = oh_base + ohl, ow0 = ow_base + owl0;
#pragma unroll
    for (int o = 0; o < COUT; ++o) {
        float4 st;
        st.x = acc[0][o]; st.y = acc[1][o]; st.z = acc[2][o]; st.w = acc[3][o];
        if (TANH) { st.x = tanhf(st.x); st.y = tanhf(st.y); st.z = tanhf(st.z); st.w = tanhf(st.w); }
        *(float4*)&y[(((size_t)b * COUT + o) * H + oh) * W + ow0] = st;
    }
}

// ---------------- 3x3 stride-2 conv v2 (parity-split LDS planes) -------------
// Block: 16 oc x (8x32 output tile); 256 thr = 4 oc-groups(waves) x 64 lanes.
// Input staged as 4 parity planes per ic: EE[8][.], OE[9][.], EO[8][.], OO[9][.]
// rows stacked in xt[.][34][36]. Tap (kh,kw) reads plane (kh parity, kw parity):
// row sr (+1 for kh=2), col sc4+p (+1 for kw=2). Norm+relu folded at staging.
// KS>1: partials to y + ks*ystride (bias only at ks==0). DOSTATS: epilogue
// wave-reduce of sum/sumsq into sacc[b*COUT+oc] / [512+...] via atomics.
template<int CIN, int COUT, int ICB, int KS, bool DOSTATS>
__global__ void __launch_bounds__(256)
conv3s2_v2(const float* __restrict__ x, const float* __restrict__ w,
           const float* __restrict__ bias,
           const float* __restrict__ mu, const float* __restrict__ rs,
           float* __restrict__ y, size_t ystride, int Hin, int Win,
           float* __restrict__ sacc)
{
    constexpr int OCB = 16;
    constexpr int NOG = COUT / OCB;
    constexpr int CK = CIN / KS;
    const int Hout = Hin >> 1, Wout = Win >> 1;
    const int z = blockIdx.z;
    const int ks = z % KS;
    const int ogb = z / KS;
    const int b = ogb / NOG;
    const int ocb = (ogb % NOG) * OCB;
    const int r0 = blockIdx.y * 8, c0 = blockIdx.x * 32;

    __shared__ float xt[ICB][34][36];   // rows: 0-7 EE, 8-16 OE, 17-24 EO, 25-33 OO
    __shared__ float wt[ICB][9][OCB];
    __shared__ float smu[CIN], srs[CIN];

    const int tid = threadIdx.x;
    if (tid < CIN) { smu[tid] = mu[b * CIN + tid]; srs[tid] = rs[b * CIN + tid]; }

    const int lane = tid & 63;
    const int og = tid >> 6;
    const int sr = lane >> 3;
    const int sc4 = (lane & 7) * 4;

    float acc[4][4];                    // [oc][pos]
#pragma unroll
    for (int o = 0; o < 4; ++o) {
        float bv = (ks == 0) ? bias[ocb + og * 4 + o] : 0.f;
#pragma unroll
        for (int p = 0; p < 4; ++p) acc[o][p] = bv;
    }

    for (int ic0 = ks * CK; ic0 < (ks + 1) * CK; ic0 += ICB) {
        __syncthreads();
        // stage parity planes (zero pad at borders)
        for (int idx = tid; idx < ICB * 34 * 33; idx += 256) {
            int c  = idx / (34 * 33);
            int rr = idx % (34 * 33);
            int r  = rr / 33, j = rr % 33;
            int ic = ic0 + c;
            int grow, gcol;
            if (r < 8)       { grow = 2 * (r0 + r);          gcol = 2 * (c0 + j); }
            else if (r < 17) { grow = 2 * (r0 + r - 8) - 1;  gcol = 2 * (c0 + j); }
            else if (r < 25) { grow = 2 * (r0 + r - 17);     gcol = 2 * (c0 + j) - 1; }
            else             { grow = 2 * (r0 + r - 25) - 1; gcol = 2 * (c0 + j) - 1; }
            float v = 0.f;
            if (grow >= 0 && grow < Hin && gcol >= 0 && gcol < Win) {
                v = x[((size_t)(b * CIN + ic)) * Hin * Win + (size_t)grow * Win + gcol];
                v = fmaxf((v - smu[ic]) * srs[ic], 0.f);
            }
            xt[c][r][j] = v;
        }
        // stage weights [icb][tap][oc]
        for (int idx = tid; idx < ICB * 9 * OCB; idx += 256) {
            int oc  = idx & (OCB - 1);
            int tap = (idx >> 4) % 9;
            int c   = idx / (9 * OCB);
            wt[c][tap][oc] = w[(size_t)(ocb + oc) * CIN * 9 + (size_t)(ic0 + c) * 9 + tap];
        }
        __syncthreads();

#pragma unroll 4
        for (int c = 0; c < ICB; ++c) {
            float ee[4], oe0[4], oe1[4], eo[5], oo0[5], oo1[5];
            {
                float4 t;
                t = *(const float4*)&xt[c][sr][sc4];
                ee[0] = t.x; ee[1] = t.y; ee[2] = t.z; ee[3] = t.w;
                t = *(const float4*)&xt[c][8 + sr][sc4];
                oe0[0] = t.x; oe0[1] = t.y; oe0[2] = t.z; oe0[3] = t.w;
                t = *(const float4*)&xt[c][9 + sr][sc4];
                oe1[0] = t.x; oe1[1] = t.y; oe1[2] = t.z; oe1[3] = t.w;
                t = *(const float4*)&xt[c][17 + sr][sc4];
                eo[0] = t.x; eo[1] = t.y; eo[2] = t.z; eo[3] = t.w;
                eo[4] = xt[c][17 + sr][sc4 + 4];
                t = *(const float4*)&xt[c][25 + sr][sc4];
                oo0[0] = t.x; oo0[1] = t.y; oo0[2] = t.z; oo0[3] = t.w;
                oo0[4] = xt[c][25 + sr][sc4 + 4];
                t = *(const float4*)&xt[c][26 + sr][sc4];
                oo1[0] = t.x; oo1[1] = t.y; oo1[2] = t.z; oo1[3] = t.w;
                oo1[4] = xt[c][26 + sr][sc4 + 4];
            }
            const float* wp = &wt[c][0][og * 4];
#define TAPFMA(TAP, XV, SH)                                                        \
            {                                                                      \
                float4 wq = *(const float4*)(wp + (TAP) * OCB);                    \
                float wv[4] = {wq.x, wq.y, wq.z, wq.w};                            \
                _Pragma("unroll")                                                  \
                for (int o = 0; o < 4; ++o)                                        \
                    _Pragma("unroll")                                              \
                    for (int p = 0; p < 4; ++p)                                    \
                        acc[o][p] += wv[o] * XV[p + SH];                           \
            }
            TAPFMA(4, ee, 0)    // (1,1)
            TAPFMA(3, eo, 0)    // (1,0)
            TAPFMA(5, eo, 1)    // (1,2)
            TAPFMA(1, oe0, 0)   // (0,1)
            TAPFMA(7, oe1, 0)   // (2,1)
            TAPFMA(0, oo0, 0)   // (0,0)
            TAPFMA(2, oo0, 1)   // (0,2)
            TAPFMA(6, oo1, 0)   // (2,0)
            TAPFMA(8, oo1, 1)   // (2,2)
#undef TAPFMA
        }
    }

    float* yb = y + (size_t)ks * ystride;
#pragma unroll
    for (int o = 0; o < 4; ++o) {
        int oc = ocb + og * 4 + o;
        float4 st;
        st.x = acc[o][0]; st.y = acc[o][1]; st.z = acc[o][2]; st.w = acc[o][3];
        *(float4*)&yb[(((size_t)(b * COUT + oc)) * Hout + r0 + sr) * Wout + c0 + sc4] = st;
    }

    if (DOSTATS) {
        float s[4], q[4];
#pragma unroll
        for (int o = 0; o < 4; ++o) {
            s[o] = acc[o][0] + acc[o][1] + acc[o][2] + acc[o][3];
            q[o] = acc[o][0] * acc[o][0] + acc[o][1] * acc[o][1]
                 + acc[o][2] * acc[o][2] + acc[o][3] * acc[o][3];
        }
#pragma unroll
        for (int off = 32; off; off >>= 1) {
#pragma unroll
            for (int o = 0; o < 4; ++o) {
                s[o] += __shfl_down(s[o], off);
                q[o] += __shfl_down(q[o], off);
            }
        }
        if (lane == 0) {
#pragma unroll
            for (int o = 0; o < 4; ++o) {
                int bc = b * COUT + ocb + og * 4 + o;
                atomicAdd(&sacc[bc], s[o]);
                atomicAdd(&sacc[512 + bc], q[o]);
            }
        }
    }
}

// ---------------- 3x3 stride-2 transposed conv (LDS + reg tiles, K-split) ----
template<int CIN, int COUT, int ICB, int KS>
__global__ void __launch_bounds__(256)
tconv3_v2(const float* __restrict__ x, const float* __restrict__ w,
          const float* __restrict__ bias,
          const float* __restrict__ mu, const float* __restrict__ rs,
          float* __restrict__ y, size_t ystride, int Hin, int Win)
{
    constexpr int OCB = 16;
    constexpr int NOG = COUT / OCB;
    constexpr int CK = CIN / KS;
    const int z = blockIdx.z;
    const int ks = z % KS;
    const int ogb = z / KS;
    const int b = ogb / NOG;
    const int ocb = (ogb % NOG) * OCB;
    const int r0 = blockIdx.y * 8, c0 = blockIdx.x * 32;
    const int Hout = Hin * 2, Wout = Win * 2;

    __shared__ float xt[ICB][9 * 36];
    __shared__ float wt[ICB][9][OCB];
    __shared__ float smu[CIN], srs[CIN];

    const int tid = threadIdx.x;
    if (tid < CIN) { smu[tid] = mu[b * CIN + tid]; srs[tid] = rs[b * CIN + tid]; }

    const int tid_s = tid & 63;
    const int og = tid >> 6;
    const int sr = tid_s >> 3;
    const int sc4 = (tid_s & 7) * 4;

    float acc[4][4][4];
#pragma unroll
    for (int o = 0; o < 4; ++o) {
        float bv = (ks == 0) ? bias[ocb + og * 4 + o] : 0.f;
#pragma unroll
        for (int pr = 0; pr < 4; ++pr)
#pragma unroll
            for (int p = 0; p < 4; ++p) acc[pr][o][p] = bv;
    }

    for (int ic0 = ks * CK; ic0 < (ks + 1) * CK; ic0 += ICB) {
        __syncthreads();
        for (int idx = tid; idx < ICB * 9 * 33; idx += 256) {
            int c  = idx / (9 * 33);
            int rr = idx % (9 * 33);
            int r  = rr / 33, col = rr % 33;
            int gr = r0 + r, gc = c0 + col;
            int ic = ic0 + c;
            float v = 0.f;
            if (gr < Hin && gc < Win) {
                v = x[((size_t)(b * CIN + ic)) * Hin * Win + (size_t)gr * Win + gc];
                v = fmaxf((v - smu[ic]) * srs[ic], 0.f);
            }
            xt[c][r * 36 + col] = v;
        }
        for (int idx = tid; idx < ICB * 9 * OCB; idx += 256) {
            int oc  = idx & (OCB - 1);
            int tap = (idx >> 4) % 9;
            int c   = idx / (9 * OCB);
            wt[c][tap][oc] = w[(size_t)(ocb + oc) * CIN * 9 + (size_t)(ic0 + c) * 9 + tap];
        }
        __syncthreads();

#pragma unroll 4
        for (int c = 0; c < ICB; ++c) {
            const float* xr = &xt[c][sr * 36 + sc4];
            float x0[5], x1[5];
            {
                float4 a = *(const float4*)xr;
                x0[0] = a.x; x0[1] = a.y; x0[2] = a.z; x0[3] = a.w; x0[4] = xr[4];
                float4 bq = *(const float4*)(xr + 36);
                x1[0] = bq.x; x1[1] = bq.y; x1[2] = bq.z; x1[3] = bq.w; x1[4] = xr[40];
            }
            const float* wp = &wt[c][0][og * 4];
#define TAPFMA(TAP, PAR, XV, SH)                                                   \
            {                                                                      \
                float4 wq = *(const float4*)(wp + (TAP) * OCB);                    \
                float wv[4] = {wq.x, wq.y, wq.z, wq.w};                            \
                _Pragma("unroll")                                                  \
                for (int o = 0; o < 4; ++o)                                        \
                    _Pragma("unroll")                                              \
                    for (int p = 0; p < 4; ++p)                                    \
                        acc[PAR][o][p] += wv[o] * XV[p + SH];                      \
            }
            TAPFMA(4, 0, x0, 0)
            TAPFMA(5, 1, x0, 0)
            TAPFMA(3, 1, x0, 1)
            TAPFMA(7, 2, x0, 0)
            TAPFMA(1, 2, x1, 0)
            TAPFMA(8, 3, x0, 0)
            TAPFMA(6, 3, x0, 1)
            TAPFMA(2, 3, x1, 0)
            TAPFMA(0, 3, x1, 1)
#undef TAPFMA
        }
    }

    float* yb = y + (size_t)ks * ystride;
    const int gr = r0 + sr, gc = c0 + sc4;
#pragma unroll
    for (int o = 0; o < 4; ++o) {
        int oc = ocb + og * 4 + o;
        float* yp = yb + (((size_t)(b * COUT + oc)) * Hout + 2 * gr) * Wout + 2 * gc;
        float4 e0, e1, d0, d1;
        e0.x = acc[0][o][0]; e0.y = acc[1][o][0]; e0.z = acc[0][o][1]; e0.w = acc[1][o][1];
        e1.x = acc[0][o][2]; e1.y = acc[1][o][2]; e1.z = acc[0][o][3]; e1.w = acc[1][o][3];
        d0.x = acc[2][o][0]; d0.y = acc[3][o][0]; d0.z = acc[2][o][1]; d0.w = acc[3][o][1];
        d1.x = acc[2][o][2]; d1.y = acc[3][o][2]; d1.z = acc[2][o][3]; d1.w = acc[3][o][3];
        *(float4*)yp = e0;
        *(float4*)(yp + 4) = e1;
        *(float4*)(yp + Wout) = d0;
        *(float4*)(yp + Wout + 4) = d1;
    }
}

// ---------------- reduce K-split partials + fused IN stats -------------------
template<int KS>
__global__ void __launch_bounds__(256)
reduce_stats(const float* __restrict__ parts, size_t pstride,
             float* __restrict__ out, float* __restrict__ acc, int HW)
{
    const int bc = blockIdx.x;
    const int chunk = HW / gridDim.y;
    const size_t base = (size_t)bc * HW + (size_t)blockIdx.y * chunk;
    float s = 0.f, ss = 0.f;
    const int n4 = chunk >> 2;
    for (int i = threadIdx.x; i < n4; i += 256) {
        float4 v = ((const float4*)(parts + base))[i];
#pragma unroll
        for (int k = 1; k < KS; ++k) {
            float4 u = ((const float4*)(parts + (size_t)k * pstride + base))[i];
            v.x += u.x; v.y += u.y; v.z += u.z; v.w += u.w;
        }
        ((float4*)(out + base))[i] = v;
        s += v.x + v.y + v.z + v.w;
        ss += v.x * v.x + v.y * v.y + v.z * v.z + v.w * v.w;
    }
#pragma unroll
    for (int off = 32; off; off >>= 1) {
        s += __shfl_down(s, off);
        ss += __shfl_down(ss, off);
    }
    __shared__ float rbuf[8];
    const int wid = threadIdx.x >> 6;
    if ((threadIdx.x & 63) == 0) { rbuf[wid] = s; rbuf[4 + wid] = ss; }
    __syncthreads();
    if (threadIdx.x == 0) {
        s = rbuf[0] + rbuf[1] + rbuf[2] + rbuf[3];
        ss = rbuf[4] + rbuf[5] + rbuf[6] + rbuf[7];
        atomicAdd(&acc[bc], s);
        atomicAdd(&acc[512 + bc], ss);
    }
}

// ---------------- instance-norm stats: partial (atomic) + finalize -----------
__global__ void __launch_bounds__(256)
in_stats_partial(const float* __restrict__ y, float* __restrict__ acc, int HW)
{
    const int bc = blockIdx.x;
    const int chunk = HW / gridDim.y;
    const float* p = y + (size_t)bc * HW + (size_t)blockIdx.y * chunk;
    float s = 0.f, ss = 0.f;
    const float4* p4 = (const float4*)p;
    const int n4 = chunk >> 2;
    for (int i = threadIdx.x; i < n4; i += 256) {
        float4 v = p4[i];
        s += v.x + v.y + v.z + v.w;
        ss += v.x * v.x + v.y * v.y + v.z * v.z + v.w * v.w;
    }
#pragma unroll
    for (int off = 32; off; off >>= 1) {
        s += __shfl_down(s, off);
        ss += __shfl_down(ss, off);
    }
    __shared__ float rbuf[8];
    const int wid = threadIdx.x >> 6;
    if ((threadIdx.x & 63) == 0) { rbuf[wid] = s; rbuf[4 + wid] = ss; }
    __syncthreads();
    if (threadIdx.x == 0) {
        s = rbuf[0] + rbuf[1] + rbuf[2] + rbuf[3];
        ss = rbuf[4] + rbuf[5] + rbuf[6] + rbuf[7];
        atomicAdd(&acc[bc], s);
        atomicAdd(&acc[512 + bc], ss);
    }
}

__global__ void in_stats_final(const float* __restrict__ acc,
                               float* __restrict__ mu, float* __restrict__ rs,
                               int BC, float invHW)
{
    int i = blockIdx.x * 256 + threadIdx.x;
    if (i < BC) {
        float m = acc[i] * invHW;
        float var = fmaxf(acc[512 + i] * invHW - m * m, 0.f);
        mu[i] = m;
        rs[i] = rsqrtf(var + EPS_IN);
    }
}

// ---------------- segment average pooling ------------------------------------
__global__ void zero_ws_k(float* __restrict__ p, int n)
{
    int i = blockIdx.x * 256 + threadIdx.x;
    if (i < n) p[i] = 0.f;
}

__global__ void __launch_bounds__(256)
seg_accum(const float* __restrict__ yT, const int* __restrict__ inst,
          float* __restrict__ seg, int HW)
{
    const int b = blockIdx.y;
    __shared__ float ls[NUM_INST * 4];
    if (threadIdx.x < NUM_INST * 4) ls[threadIdx.x] = 0.f;
    __syncthreads();
    const float* p0 = yT + (size_t)b * 3 * HW;
    const int* ip = inst + (size_t)b * HW;
    for (int i = blockIdx.x * 256 + threadIdx.x; i < HW; i += gridDim.x * 256) {
        int id = ip[i];
        atomicAdd(&ls[id * 4 + 0], p0[i]);
        atomicAdd(&ls[id * 4 + 1], p0[HW + i]);
        atomicAdd(&ls[id * 4 + 2], p0[2 * (size_t)HW + i]);
        atomicAdd(&ls[id * 4 + 3], 1.f);
    }
    __syncthreads();
    if (threadIdx.x < NUM_INST * 4)
        atomicAdd(&seg[b * NUM_INST * 4 + threadIdx.x], ls[threadIdx.x]);
}

__global__ void seg_means_k(const float* __restrict__ seg, float* __restrict__ means)
{
    int i = threadIdx.x;
    if (i < 2 * NUM_INST * 3) {
        int bi = i / 3, c = i % 3;
        float cnt = seg[bi * 4 + 3];
        means[i] = seg[bi * 4 + c] / fmaxf(cnt, 1.f);
    }
}

__global__ void __launch_bounds__(256)
seg_scatter(const int* __restrict__ inst, const float* __restrict__ means,
            float* __restrict__ out, int HW)
{
    const int b = blockIdx.y;
    for (int i = blockIdx.x * 256 + threadIdx.x; i < HW; i += gridDim.x * 256) {
        int id = inst[(size_t)b * HW + i];
        const float* m = &means[(b * NUM_INST + id) * 3];
        out[((size_t)b * 3 + 0) * HW + i] = m[0];
        out[((size_t)b * 3 + 1) * HW + i] = m[1];
        out[((size_t)b * 3 + 2) * HW + i] = m[2];
    }
}

// ---------------- driver -----------------------------------------------------
extern "C" void kernel_launch(void* const* d_in, const int* in_sizes, int n_in,
                              void* d_out, int out_size, void* d_ws, size_t ws_size,
                              hipStream_t stream)
{
    const float* x_in = (const float*)d_in[0];
    const int* inst = (const int*)d_in[1];
    const float* e0w = (const float*)d_in[2];  const float* e0b = (const float*)d_in[3];
    const float* e1w = (const float*)d_in[4];  const float* e1b = (const float*)d_in[5];
    const float* e2w = (const float*)d_in[6];  const float* e2b = (const float*)d_in[7];
    const float* e3w = (const float*)d_in[8];  const float* e3b = (const float*)d_in[9];
    const float* e4w = (const float*)d_in[10]; const float* e4b = (const float*)d_in[11];
    const float* d0w = (const float*)d_in[12]; const float* d0b = (const float*)d_in[13];
    const float* d1w = (const float*)d_in[14]; const float* d1b = (const float*)d_in[15];
    const float* d2w = (const float*)d_in[16]; const float* d2b = (const float*)d_in[17];
    const float* d3w = (const float*)d_in[18]; const float* d3b = (const float*)d_in[19];
    const float* d4w = (const float*)d_in[20]; const float* d4b = (const float*)d_in[21];
    float* outp = (float*)d_out;

    float* bufA = (float*)d_ws;                       // 16777216 floats
    float* bufB = bufA + 16777216;                    // 8388608 floats
    float* st   = bufB + 8388608;                     // 9 layers x 1024 (mu|rs)
    float* acc  = st + 9 * 1024;                      // 9 layers x 1024 (sum|ss)
    float* seg  = acc + 9 * 1024;                     // 2*32*4
    float* means = seg + 2 * NUM_INST * 4;            // 2*32*3

    const dim3 blk(256);
    const int H = 512, W = 1024;

    {
        int nz = 9 * 1024 + 2 * NUM_INST * 4;
        zero_ws_k<<<dim3((nz + 255) / 256), blk, 0, stream>>>(acc, nz);
    }

#define STATS(buf, L, C, HWv)                                                        \
    in_stats_partial<<<dim3(2 * (C), 8), blk, 0, stream>>>((buf), acc + (L) * 1024, (HWv)); \
    in_stats_final<<<dim3(2), blk, 0, stream>>>(acc + (L) * 1024, st + (L) * 1024,          \
                                                st + (L) * 1024 + 512, 2 * (C),             \
                                                1.0f / (HWv));

    // L0: e0 7x7 reflect, 3->16 -> bufA
    conv7_lds<3, 16, 3, false, false><<<dim3(W / 32, H / 32, 2), blk, 0, stream>>>(
        x_in, e0w, e0b, nullptr, nullptr, bufA, H, W);
    STATS(bufA, 0, 16, H * W);

    // L1: 16->32 -> bufB (stats fused)
    conv3s2_v2<16, 32, 8, 1, true><<<dim3(16, 32, 2 * 2), blk, 0, stream>>>(
        bufA, e1w, e1b, st + 0 * 1024, st + 0 * 1024 + 512, bufB, 0, 512, 1024,
        acc + 1 * 1024);
    in_stats_final<<<dim3(2), blk, 0, stream>>>(acc + 1 * 1024, st + 1 * 1024,
                                                st + 1 * 1024 + 512, 2 * 32,
                                                1.0f / (256 * 512));

    // L2: 32->64 -> bufA (stats fused)
    conv3s2_v2<32, 64, 8, 1, true><<<dim3(8, 16, 2 * 4), blk, 0, stream>>>(
        bufB, e2w, e2b, st + 1 * 1024, st + 1 * 1024 + 512, bufA, 0, 256, 512,
        acc + 2 * 1024);
    in_stats_final<<<dim3(2), blk, 0, stream>>>(acc + 2 * 1024, st + 2 * 1024,
                                                st + 2 * 1024 + 512, 2 * 64,
                                                1.0f / (128 * 256));

    // L3: 64->128 -> bufB (stats fused)
    conv3s2_v2<64, 128, 8, 1, true><<<dim3(4, 8, 2 * 8), blk, 0, stream>>>(
        bufA, e3w, e3b, st + 2 * 1024, st + 2 * 1024 + 512, bufB, 0, 128, 256,
        acc + 3 * 1024);
    in_stats_final<<<dim3(2), blk, 0, stream>>>(acc + 3 * 1024, st + 3 * 1024,
                                                st + 3 * 1024 + 512, 2 * 128,
                                                1.0f / (64 * 128));

    // L4: 128->256, KS=2. Partials bufA[1M..3M), out -> bufA[0..1M)
    {
        const size_t PS = 1048576;                    // 2*256*32*64
        float* parts = bufA + 1048576;
        conv3s2_v2<128, 256, 8, 2, false><<<dim3(2, 4, 2 * 16 * 2), blk, 0, stream>>>(
            bufB, e4w, e4b, st + 3 * 1024, st + 3 * 1024 + 512, parts, PS, 64, 128,
            nullptr);
        reduce_stats<2><<<dim3(2 * 256, 8), blk, 0, stream>>>(
            parts, PS, bufA, acc + 4 * 1024, 32 * 64);
        in_stats_final<<<dim3(2), blk, 0, stream>>>(acc + 4 * 1024, st + 4 * 1024,
                                                    st + 4 * 1024 + 512, 2 * 256,
                                                    1.0f / (32 * 64));
    }

    // D0: tconv 256->128, KS=4. Partials in bufA[2M..10M), out -> bufB[0..2M)
    {
        const size_t PS = 2097152;                    // 2*128*64*128
        float* parts = bufA + 2097152;
        tconv3_v2<256, 128, 16, 4><<<dim3(2, 4, 2 * 8 * 4), blk, 0, stream>>>(
            bufA, d0w, d0b, st + 4 * 1024, st + 4 * 1024 + 512, parts, PS, 32, 64);
        reduce_stats<4><<<dim3(2 * 128, 8), blk, 0, stream>>>(
            parts, PS, bufB, acc + 5 * 1024, 64 * 128);
        in_stats_final<<<dim3(2), blk, 0, stream>>>(acc + 5 * 1024, st + 5 * 1024,
                                                    st + 5 * 1024 + 512, 2 * 128,
                                                    1.0f / (64 * 128));
    }

    // D1: tconv 128->64, KS=2. Partials in bufA[8M..16M), out -> bufA[0..4M)
    {
        const size_t PS = 4194304;                    // 2*64*128*256
        float* parts = bufA + 8388608;
        tconv3_v2<128, 64, 16, 2><<<dim3(4, 8, 2 * 4 * 2), blk, 0, stream>>>(
            bufB, d1w, d1b, st + 5 * 1024, st + 5 * 1024 + 512, parts, PS, 64, 128);
        reduce_stats<2><<<dim3(2 * 64, 8), blk, 0, stream>>>(
            parts, PS, bufA, acc + 6 * 1024, 128 * 256);
        in_stats_final<<<dim3(2), blk, 0, stream>>>(acc + 6 * 1024, st + 6 * 1024,
                                                    st + 6 * 1024 + 512, 2 * 64,
                                                    1.0f / (128 * 256));
    }

    // D2: tconv 64->32 -> bufB
    tconv3_v2<64, 32, 16, 1><<<dim3(256 / 32, 128 / 8, 2 * 2), blk, 0, stream>>>(
        bufA, d2w, d2b, st + 6 * 1024, st + 6 * 1024 + 512, bufB, 0, 128, 256);
    STATS(bufB, 7, 32, 256 * 512);

    // D3: tconv 32->16 -> bufA
    tconv3_v2<32, 16, 16, 1><<<dim3(512 / 32, 256 / 8, 2 * 1), blk, 0, stream>>>(
        bufB, d3w, d3b, st + 7 * 1024, st + 7 * 1024 + 512, bufA, 0, 256, 512);
    STATS(bufA, 8, 16, H * W);

    // D4: 7x7 reflect 16->3 + tanh -> bufB
    conv7_lds<16, 3, 4, true, true><<<dim3(W / 32, H / 32, 2), blk, 0, stream>>>(
        bufA, d4w, d4b, st + 8 * 1024, st + 8 * 1024 + 512, bufB, H, W);

    // segment average pool
    seg_accum<<<dim3(256, 2), blk, 0, stream>>>(bufB, inst, seg, H * W);
    seg_means_k<<<dim3(1), blk, 0, stream>>>(seg, means);
    seg_scatter<<<dim3(512, 2), blk, 0, stream>>>(inst, means, outp, H * W);

#undef STATS
}

// Round 6
// 1311.123 us; speedup vs baseline: 1.2596x; 1.2596x over previous
//
#include <hip/hip_runtime.h>
#include <cstddef>

#define NUM_INST 32
#define EPS_IN 1e-5f

__device__ __forceinline__ int reflect_idx(int i, int n) {
    if (i < 0) i = -i;
    else if (i >= n) i = 2 * n - 2 - i;
    return i;
}

// ---------------- 7x7 reflect-pad conv, LDS-staged ---------------------------
template<int CIN, int COUT, int NCH, bool NORM, bool TANH>
__global__ void __launch_bounds__(256, 4)
conv7_lds(const float* __restrict__ x, const float* __restrict__ w,
          const float* __restrict__ bias,
          const float* __restrict__ mu, const float* __restrict__ rs,
          float* __restrict__ y, int H, int W)
{
    constexpr int COUTP = (COUT + 3) & ~3;
    __shared__ float wsm[CIN * 49 * COUTP];    // [ic][kh][kw][ocp]
    __shared__ float tile[NCH][38 * 39];
    __shared__ float smu[CIN], srs[CIN];
    const int tid = threadIdx.x;
    const int b = blockIdx.z;

    for (int idx = tid; idx < CIN * 49 * COUTP; idx += 256) {
        int ocp = idx % COUTP;
        int r   = idx / COUTP;
        wsm[idx] = (ocp < COUT) ? w[(size_t)ocp * CIN * 49 + r] : 0.f;
    }
    if (NORM && tid < CIN) { smu[tid] = mu[b * CIN + tid]; srs[tid] = rs[b * CIN + tid]; }

    const int oh_base = blockIdx.y * 32, ow_base = blockIdx.x * 32;
    const int ohl = tid >> 3, owl0 = (tid & 7) * 4;

    float acc[4][COUT];
#pragma unroll
    for (int o = 0; o < COUT; ++o) {
        float bv = bias[o];
#pragma unroll
        for (int j = 0; j < 4; ++j) acc[j][o] = bv;
    }

    for (int ic0 = 0; ic0 < CIN; ic0 += NCH) {
        __syncthreads();
        for (int idx = tid; idx < NCH * 1444; idx += 256) {
            int c = idx / 1444;
            int rr = idx % 1444;
            int r = rr / 38, col = rr % 38;
            int gy = reflect_idx(oh_base - 3 + r, H);
            int gx = reflect_idx(ow_base - 3 + col, W);
            float v = x[((size_t)(b * CIN + ic0 + c)) * H * W + (size_t)gy * W + gx];
            if (NORM) v = fmaxf((v - smu[ic0 + c]) * srs[ic0 + c], 0.f);
            tile[c][r * 39 + col] = v;
        }
        __syncthreads();
#pragma unroll
        for (int cc = 0; cc < NCH; ++cc) {
            const float* tp = &tile[cc][0];
            const float4* wp4 = (const float4*)&wsm[(ic0 + cc) * 49 * COUTP];
#pragma unroll
            for (int kh = 0; kh < 7; ++kh) {
                float rv[10];
#pragma unroll
                for (int i = 0; i < 10; ++i) rv[i] = tp[(ohl + kh) * 39 + owl0 + i];
#pragma unroll
                for (int kw = 0; kw < 7; ++kw) {
#pragma unroll
                    for (int o4 = 0; o4 < COUTP / 4; ++o4) {
                        float4 wv = wp4[(kh * 7 + kw) * (COUTP / 4) + o4];
#pragma unroll
                        for (int j = 0; j < 4; ++j) {
                            if (o4 * 4 + 0 < COUT) acc[j][o4 * 4 + 0] += rv[kw + j] * wv.x;
                            if (o4 * 4 + 1 < COUT) acc[j][o4 * 4 + 1] += rv[kw + j] * wv.y;
                            if (o4 * 4 + 2 < COUT) acc[j][o4 * 4 + 2] += rv[kw + j] * wv.z;
                            if (o4 * 4 + 3 < COUT) acc[j][o4 * 4 + 3] += rv[kw + j] * wv.w;
                        }
                    }
                }
            }
        }
    }

    const int oh = oh_base + ohl, ow0 = ow_base + owl0;
#pragma unroll
    for (int o = 0; o < COUT; ++o) {
        float4 st;
        st.x = acc[0][o]; st.y = acc[1][o]; st.z = acc[2][o]; st.w = acc[3][o];
        if (TANH) { st.x = tanhf(st.x); st.y = tanhf(st.y); st.z = tanhf(st.z); st.w = tanhf(st.w); }
        *(float4*)&y[(((size_t)b * COUT + o) * H + oh) * W + ow0] = st;
    }
}

// ---------------- 3x3 stride-2 conv v3 (col-parity LDS, coalesced staging) ---
// Block: OCB=32 oc x (8x32 output tile); 256 thr = 4 waves x 64 lanes.
// Lane: sr=lane>>3 (out row), sc4=(lane&7)*4 (out col base); wave og: 8 oc.
// LDS xt[c][17][2][36]: 17 input rows (2*r0-1 ..), plane0 = even cols
// (2*(c0+j)), plane1 = odd cols shifted (o[j] = col 2*(c0+j)-1).
// Staged via aligned float2 reads -> fully coalesced. Norm+relu at staging.
// Tap (kh,kw): row ir=2*sr+kh; kw=0 -> o4[sc4..], kw=1 -> e4[sc4..],
// kw=2 -> o4[sc4+1..]+o[sc4+4]. KS>1: partials to y + ks*ystride.
template<int CIN, int COUT, int ICB, int KS, bool DOSTATS>
__global__ void __launch_bounds__(256)
conv3s2_v3(const float* __restrict__ x, const float* __restrict__ w,
           const float* __restrict__ bias,
           const float* __restrict__ mu, const float* __restrict__ rs,
           float* __restrict__ y, size_t ystride, int Hin, int Win,
           float* __restrict__ sacc)
{
    constexpr int OCB = 32;
    constexpr int NOG = COUT / OCB;
    constexpr int CK = CIN / KS;
    const int Hout = Hin >> 1, Wout = Win >> 1;
    const int z = blockIdx.z;
    const int ks = z % KS;
    const int ogb = z / KS;
    const int b = ogb / NOG;
    const int ocb = (ogb % NOG) * OCB;
    const int r0 = blockIdx.y * 8, c0 = blockIdx.x * 32;

    __shared__ float xt[ICB][17][2][36];
    __shared__ float wt[ICB][9][OCB];
    __shared__ float smu[CIN], srs[CIN];

    const int tid = threadIdx.x;
    if (tid < CIN) { smu[tid] = mu[b * CIN + tid]; srs[tid] = rs[b * CIN + tid]; }

    const int lane = tid & 63;
    const int og = tid >> 6;
    const int sr = lane >> 3;
    const int sc4 = (lane & 7) * 4;

    float acc[8][4];                    // [oc][pos]
#pragma unroll
    for (int o = 0; o < 8; ++o) {
        float bv = (ks == 0) ? bias[ocb + og * 8 + o] : 0.f;
#pragma unroll
        for (int p = 0; p < 4; ++p) acc[o][p] = bv;
    }

    for (int ic0 = ks * CK; ic0 < (ks + 1) * CK; ic0 += ICB) {
        __syncthreads();
        // stage: aligned float2 pairs -> even/odd planes
        for (int idx = tid; idx < ICB * 17 * 34; idx += 256) {
            int c   = idx / (17 * 34);
            int rem = idx % (17 * 34);
            int ir  = rem / 34, j = rem % 34;
            int ic  = ic0 + c;
            int grow = 2 * r0 - 1 + ir;
            const float* xp = x + ((size_t)(b * CIN + ic)) * Hin * Win;
            if (j < 33) {
                int gcol = 2 * (c0 + j);
                float v0 = 0.f, v1 = 0.f;
                if (grow >= 0 && grow < Hin && gcol < Win) {
                    float2 t = *(const float2*)&xp[(size_t)grow * Win + gcol];
                    float m = smu[ic], rr = srs[ic];
                    v0 = fmaxf((t.x - m) * rr, 0.f);
                    v1 = fmaxf((t.y - m) * rr, 0.f);
                }
                xt[c][ir][0][j] = v0;
                xt[c][ir][1][j + 1] = v1;
            } else {
                int gcol = 2 * c0 - 1;
                float v = 0.f;
                if (grow >= 0 && grow < Hin && gcol >= 0) {
                    v = xp[(size_t)grow * Win + gcol];
                    v = fmaxf((v - smu[ic]) * srs[ic], 0.f);
                }
                xt[c][ir][1][0] = v;
            }
        }
        // stage weights [icb][tap][oc]
        for (int idx = tid; idx < ICB * 9 * OCB; idx += 256) {
            int oc  = idx & (OCB - 1);
            int tap = (idx >> 5) % 9;
            int c   = idx / (9 * OCB);
            wt[c][tap][oc] = w[(size_t)(ocb + oc) * CIN * 9 + (size_t)(ic0 + c) * 9 + tap];
        }
        __syncthreads();

#pragma unroll 2
        for (int c = 0; c < ICB; ++c) {
            const float* wbase = &wt[c][0][og * 8];
#pragma unroll
            for (int kh = 0; kh < 3; ++kh) {
                const float* row = &xt[c][2 * sr + kh][0][0];
                float4 e4 = *(const float4*)&row[sc4];
                float4 o4 = *(const float4*)&row[36 + sc4];
                float oX = row[36 + sc4 + 4];
                float xk0[4] = {o4.x, o4.y, o4.z, o4.w};
                float xk1[4] = {e4.x, e4.y, e4.z, e4.w};
                float xk2[4] = {o4.y, o4.z, o4.w, oX};
#pragma unroll
                for (int kw = 0; kw < 3; ++kw) {
                    const float* wp = wbase + (kh * 3 + kw) * OCB;
                    float4 wa = *(const float4*)wp;
                    float4 wb = *(const float4*)(wp + 4);
                    float wv[8] = {wa.x, wa.y, wa.z, wa.w, wb.x, wb.y, wb.z, wb.w};
                    const float* xv = (kw == 0) ? xk0 : (kw == 1) ? xk1 : xk2;
#pragma unroll
                    for (int o = 0; o < 8; ++o)
#pragma unroll
                        for (int p = 0; p < 4; ++p)
                            acc[o][p] += wv[o] * xv[p];
                }
            }
        }
    }

    float* yb = y + (size_t)ks * ystride;
#pragma unroll
    for (int o = 0; o < 8; ++o) {
        int oc = ocb + og * 8 + o;
        float4 st;
        st.x = acc[o][0]; st.y = acc[o][1]; st.z = acc[o][2]; st.w = acc[o][3];
        *(float4*)&yb[(((size_t)(b * COUT + oc)) * Hout + r0 + sr) * Wout + c0 + sc4] = st;
    }

    if (DOSTATS) {
        float s[8], q[8];
#pragma unroll
        for (int o = 0; o < 8; ++o) {
            s[o] = acc[o][0] + acc[o][1] + acc[o][2] + acc[o][3];
            q[o] = acc[o][0] * acc[o][0] + acc[o][1] * acc[o][1]
                 + acc[o][2] * acc[o][2] + acc[o][3] * acc[o][3];
        }
#pragma unroll
        for (int off = 32; off; off >>= 1) {
#pragma unroll
            for (int o = 0; o < 8; ++o) {
                s[o] += __shfl_down(s[o], off);
                q[o] += __shfl_down(q[o], off);
            }
        }
        if (lane == 0) {
#pragma unroll
            for (int o = 0; o < 8; ++o) {
                int bc = b * COUT + ocb + og * 8 + o;
                atomicAdd(&sacc[bc], s[o]);
                atomicAdd(&sacc[512 + bc], q[o]);
            }
        }
    }
}

// ---------------- 3x3 stride-2 transposed conv (LDS + reg tiles, K-split) ----
template<int CIN, int COUT, int ICB, int KS>
__global__ void __launch_bounds__(256)
tconv3_v2(const float* __restrict__ x, const float* __restrict__ w,
          const float* __restrict__ bias,
          const float* __restrict__ mu, const float* __restrict__ rs,
          float* __restrict__ y, size_t ystride, int Hin, int Win)
{
    constexpr int OCB = 16;
    constexpr int NOG = COUT / OCB;
    constexpr int CK = CIN / KS;
    const int z = blockIdx.z;
    const int ks = z % KS;
    const int ogb = z / KS;
    const int b = ogb / NOG;
    const int ocb = (ogb % NOG) * OCB;
    const int r0 = blockIdx.y * 8, c0 = blockIdx.x * 32;
    const int Hout = Hin * 2, Wout = Win * 2;

    __shared__ float xt[ICB][9 * 36];
    __shared__ float wt[ICB][9][OCB];
    __shared__ float smu[CIN], srs[CIN];

    const int tid = threadIdx.x;
    if (tid < CIN) { smu[tid] = mu[b * CIN + tid]; srs[tid] = rs[b * CIN + tid]; }

    const int tid_s = tid & 63;
    const int og = tid >> 6;
    const int sr = tid_s >> 3;
    const int sc4 = (tid_s & 7) * 4;

    float acc[4][4][4];
#pragma unroll
    for (int o = 0; o < 4; ++o) {
        float bv = (ks == 0) ? bias[ocb + og * 4 + o] : 0.f;
#pragma unroll
        for (int pr = 0; pr < 4; ++pr)
#pragma unroll
            for (int p = 0; p < 4; ++p) acc[pr][o][p] = bv;
    }

    for (int ic0 = ks * CK; ic0 < (ks + 1) * CK; ic0 += ICB) {
        __syncthreads();
        for (int idx = tid; idx < ICB * 9 * 33; idx += 256) {
            int c  = idx / (9 * 33);
            int rr = idx % (9 * 33);
            int r  = rr / 33, col = rr % 33;
            int gr = r0 + r, gc = c0 + col;
            int ic = ic0 + c;
            float v = 0.f;
            if (gr < Hin && gc < Win) {
                v = x[((size_t)(b * CIN + ic)) * Hin * Win + (size_t)gr * Win + gc];
                v = fmaxf((v - smu[ic]) * srs[ic], 0.f);
            }
            xt[c][r * 36 + col] = v;
        }
        for (int idx = tid; idx < ICB * 9 * OCB; idx += 256) {
            int oc  = idx & (OCB - 1);
            int tap = (idx >> 4) % 9;
            int c   = idx / (9 * OCB);
            wt[c][tap][oc] = w[(size_t)(ocb + oc) * CIN * 9 + (size_t)(ic0 + c) * 9 + tap];
        }
        __syncthreads();

#pragma unroll 4
        for (int c = 0; c < ICB; ++c) {
            const float* xr = &xt[c][sr * 36 + sc4];
            float x0[5], x1[5];
            {
                float4 a = *(const float4*)xr;
                x0[0] = a.x; x0[1] = a.y; x0[2] = a.z; x0[3] = a.w; x0[4] = xr[4];
                float4 bq = *(const float4*)(xr + 36);
                x1[0] = bq.x; x1[1] = bq.y; x1[2] = bq.z; x1[3] = bq.w; x1[4] = xr[40];
            }
            const float* wp = &wt[c][0][og * 4];
#define TAPFMA(TAP, PAR, XV, SH)                                                   \
            {                                                                      \
                float4 wq = *(const float4*)(wp + (TAP) * OCB);                    \
                float wv[4] = {wq.x, wq.y, wq.z, wq.w};                            \
                _Pragma("unroll")                                                  \
                for (int o = 0; o < 4; ++o)                                        \
                    _Pragma("unroll")                                              \
                    for (int p = 0; p < 4; ++p)                                    \
                        acc[PAR][o][p] += wv[o] * XV[p + SH];                      \
            }
            TAPFMA(4, 0, x0, 0)
            TAPFMA(5, 1, x0, 0)
            TAPFMA(3, 1, x0, 1)
            TAPFMA(7, 2, x0, 0)
            TAPFMA(1, 2, x1, 0)
            TAPFMA(8, 3, x0, 0)
            TAPFMA(6, 3, x0, 1)
            TAPFMA(2, 3, x1, 0)
            TAPFMA(0, 3, x1, 1)
#undef TAPFMA
        }
    }

    float* yb = y + (size_t)ks * ystride;
    const int gr = r0 + sr, gc = c0 + sc4;
#pragma unroll
    for (int o = 0; o < 4; ++o) {
        int oc = ocb + og * 4 + o;
        float* yp = yb + (((size_t)(b * COUT + oc)) * Hout + 2 * gr) * Wout + 2 * gc;
        float4 e0, e1, d0, d1;
        e0.x = acc[0][o][0]; e0.y = acc[1][o][0]; e0.z = acc[0][o][1]; e0.w = acc[1][o][1];
        e1.x = acc[0][o][2]; e1.y = acc[1][o][2]; e1.z = acc[0][o][3]; e1.w = acc[1][o][3];
        d0.x = acc[2][o][0]; d0.y = acc[3][o][0]; d0.z = acc[2][o][1]; d0.w = acc[3][o][1];
        d1.x = acc[2][o][2]; d1.y = acc[3][o][2]; d1.z = acc[2][o][3]; d1.w = acc[3][o][3];
        *(float4*)yp = e0;
        *(float4*)(yp + 4) = e1;
        *(float4*)(yp + Wout) = d0;
        *(float4*)(yp + Wout + 4) = d1;
    }
}

// ---------------- reduce K-split partials + fused IN stats -------------------
template<int KS>
__global__ void __launch_bounds__(256)
reduce_stats(const float* __restrict__ parts, size_t pstride,
             float* __restrict__ out, float* __restrict__ acc, int HW)
{
    const int bc = blockIdx.x;
    const int chunk = HW / gridDim.y;
    const size_t base = (size_t)bc * HW + (size_t)blockIdx.y * chunk;
    float s = 0.f, ss = 0.f;
    const int n4 = chunk >> 2;
    for (int i = threadIdx.x; i < n4; i += 256) {
        float4 v = ((const float4*)(parts + base))[i];
#pragma unroll
        for (int k = 1; k < KS; ++k) {
            float4 u = ((const float4*)(parts + (size_t)k * pstride + base))[i];
            v.x += u.x; v.y += u.y; v.z += u.z; v.w += u.w;
        }
        ((float4*)(out + base))[i] = v;
        s += v.x + v.y + v.z + v.w;
        ss += v.x * v.x + v.y * v.y + v.z * v.z + v.w * v.w;
    }
#pragma unroll
    for (int off = 32; off; off >>= 1) {
        s += __shfl_down(s, off);
        ss += __shfl_down(ss, off);
    }
    __shared__ float rbuf[8];
    const int wid = threadIdx.x >> 6;
    if ((threadIdx.x & 63) == 0) { rbuf[wid] = s; rbuf[4 + wid] = ss; }
    __syncthreads();
    if (threadIdx.x == 0) {
        s = rbuf[0] + rbuf[1] + rbuf[2] + rbuf[3];
        ss = rbuf[4] + rbuf[5] + rbuf[6] + rbuf[7];
        atomicAdd(&acc[bc], s);
        atomicAdd(&acc[512 + bc], ss);
    }
}

// ---------------- instance-norm stats: partial (atomic) + finalize -----------
__global__ void __launch_bounds__(256)
in_stats_partial(const float* __restrict__ y, float* __restrict__ acc, int HW)
{
    const int bc = blockIdx.x;
    const int chunk = HW / gridDim.y;
    const float* p = y + (size_t)bc * HW + (size_t)blockIdx.y * chunk;
    float s = 0.f, ss = 0.f;
    const float4* p4 = (const float4*)p;
    const int n4 = chunk >> 2;
    for (int i = threadIdx.x; i < n4; i += 256) {
        float4 v = p4[i];
        s += v.x + v.y + v.z + v.w;
        ss += v.x * v.x + v.y * v.y + v.z * v.z + v.w * v.w;
    }
#pragma unroll
    for (int off = 32; off; off >>= 1) {
        s += __shfl_down(s, off);
        ss += __shfl_down(ss, off);
    }
    __shared__ float rbuf[8];
    const int wid = threadIdx.x >> 6;
    if ((threadIdx.x & 63) == 0) { rbuf[wid] = s; rbuf[4 + wid] = ss; }
    __syncthreads();
    if (threadIdx.x == 0) {
        s = rbuf[0] + rbuf[1] + rbuf[2] + rbuf[3];
        ss = rbuf[4] + rbuf[5] + rbuf[6] + rbuf[7];
        atomicAdd(&acc[bc], s);
        atomicAdd(&acc[512 + bc], ss);
    }
}

__global__ void in_stats_final(const float* __restrict__ acc,
                               float* __restrict__ mu, float* __restrict__ rs,
                               int BC, float invHW)
{
    int i = blockIdx.x * 256 + threadIdx.x;
    if (i < BC) {
        float m = acc[i] * invHW;
        float var = fmaxf(acc[512 + i] * invHW - m * m, 0.f);
        mu[i] = m;
        rs[i] = rsqrtf(var + EPS_IN);
    }
}

// ---------------- segment average pooling ------------------------------------
__global__ void zero_ws_k(float* __restrict__ p, int n)
{
    int i = blockIdx.x * 256 + threadIdx.x;
    if (i < n) p[i] = 0.f;
}

__global__ void __launch_bounds__(256)
seg_accum(const float* __restrict__ yT, const int* __restrict__ inst,
          float* __restrict__ seg, int HW)
{
    const int b = blockIdx.y;
    __shared__ float ls[NUM_INST * 4];
    if (threadIdx.x < NUM_INST * 4) ls[threadIdx.x] = 0.f;
    __syncthreads();
    const float* p0 = yT + (size_t)b * 3 * HW;
    const int* ip = inst + (size_t)b * HW;
    for (int i = blockIdx.x * 256 + threadIdx.x; i < HW; i += gridDim.x * 256) {
        int id = ip[i];
        atomicAdd(&ls[id * 4 + 0], p0[i]);
        atomicAdd(&ls[id * 4 + 1], p0[HW + i]);
        atomicAdd(&ls[id * 4 + 2], p0[2 * (size_t)HW + i]);
        atomicAdd(&ls[id * 4 + 3], 1.f);
    }
    __syncthreads();
    if (threadIdx.x < NUM_INST * 4)
        atomicAdd(&seg[b * NUM_INST * 4 + threadIdx.x], ls[threadIdx.x]);
}

__global__ void seg_means_k(const float* __restrict__ seg, float* __restrict__ means)
{
    int i = threadIdx.x;
    if (i < 2 * NUM_INST * 3) {
        int bi = i / 3, c = i % 3;
        float cnt = seg[bi * 4 + 3];
        means[i] = seg[bi * 4 + c] / fmaxf(cnt, 1.f);
    }
}

__global__ void __launch_bounds__(256)
seg_scatter(const int* __restrict__ inst, const float* __restrict__ means,
            float* __restrict__ out, int HW)
{
    const int b = blockIdx.y;
    for (int i = blockIdx.x * 256 + threadIdx.x; i < HW; i += gridDim.x * 256) {
        int id = inst[(size_t)b * HW + i];
        const float* m = &means[(b * NUM_INST + id) * 3];
        out[((size_t)b * 3 + 0) * HW + i] = m[0];
        out[((size_t)b * 3 + 1) * HW + i] = m[1];
        out[((size_t)b * 3 + 2) * HW + i] = m[2];
    }
}

// ---------------- driver -----------------------------------------------------
extern "C" void kernel_launch(void* const* d_in, const int* in_sizes, int n_in,
                              void* d_out, int out_size, void* d_ws, size_t ws_size,
                              hipStream_t stream)
{
    const float* x_in = (const float*)d_in[0];
    const int* inst = (const int*)d_in[1];
    const float* e0w = (const float*)d_in[2];  const float* e0b = (const float*)d_in[3];
    const float* e1w = (const float*)d_in[4];  const float* e1b = (const float*)d_in[5];
    const float* e2w = (const float*)d_in[6];  const float* e2b = (const float*)d_in[7];
    const float* e3w = (const float*)d_in[8];  const float* e3b = (const float*)d_in[9];
    const float* e4w = (const float*)d_in[10]; const float* e4b = (const float*)d_in[11];
    const float* d0w = (const float*)d_in[12]; const float* d0b = (const float*)d_in[13];
    const float* d1w = (const float*)d_in[14]; const float* d1b = (const float*)d_in[15];
    const float* d2w = (const float*)d_in[16]; const float* d2b = (const float*)d_in[17];
    const float* d3w = (const float*)d_in[18]; const float* d3b = (const float*)d_in[19];
    const float* d4w = (const float*)d_in[20]; const float* d4b = (const float*)d_in[21];
    float* outp = (float*)d_out;

    float* bufA = (float*)d_ws;                       // 16777216 floats
    float* bufB = bufA + 16777216;                    // 8388608 floats
    float* st   = bufB + 8388608;                     // 9 layers x 1024 (mu|rs)
    float* acc  = st + 9 * 1024;                      // 9 layers x 1024 (sum|ss)
    float* seg  = acc + 9 * 1024;                     // 2*32*4
    float* means = seg + 2 * NUM_INST * 4;            // 2*32*3

    const dim3 blk(256);
    const int H = 512, W = 1024;

    {
        int nz = 9 * 1024 + 2 * NUM_INST * 4;
        zero_ws_k<<<dim3((nz + 255) / 256), blk, 0, stream>>>(acc, nz);
    }

#define STATS(buf, L, C, HWv)                                                        \
    in_stats_partial<<<dim3(2 * (C), 8), blk, 0, stream>>>((buf), acc + (L) * 1024, (HWv)); \
    in_stats_final<<<dim3(2), blk, 0, stream>>>(acc + (L) * 1024, st + (L) * 1024,          \
                                                st + (L) * 1024 + 512, 2 * (C),             \
                                                1.0f / (HWv));

    // L0: e0 7x7 reflect, 3->16 -> bufA[0..16.77M) (full)
    conv7_lds<3, 16, 3, false, false><<<dim3(W / 32, H / 32, 2), blk, 0, stream>>>(
        x_in, e0w, e0b, nullptr, nullptr, bufA, H, W);
    STATS(bufA, 0, 16, H * W);

    // L1: 16->32 -> bufB (full, stats fused)
    conv3s2_v3<16, 32, 8, 1, true><<<dim3(16, 32, 2), blk, 0, stream>>>(
        bufA, e1w, e1b, st + 0 * 1024, st + 0 * 1024 + 512, bufB, 0, 512, 1024,
        acc + 1 * 1024);
    in_stats_final<<<dim3(2), blk, 0, stream>>>(acc + 1 * 1024, st + 1 * 1024,
                                                st + 1 * 1024 + 512, 2 * 32,
                                                1.0f / (256 * 512));

    // L2: 32->64 -> bufA[0..4.19M) (stats fused)
    conv3s2_v3<32, 64, 8, 1, true><<<dim3(8, 16, 4), blk, 0, stream>>>(
        bufB, e2w, e2b, st + 1 * 1024, st + 1 * 1024 + 512, bufA, 0, 256, 512,
        acc + 2 * 1024);
    in_stats_final<<<dim3(2), blk, 0, stream>>>(acc + 2 * 1024, st + 2 * 1024,
                                                st + 2 * 1024 + 512, 2 * 64,
                                                1.0f / (128 * 256));

    // L3: 64->128, KS=4. in bufA[0..4.19M); partials bufA[4.19M..12.58M);
    // out -> bufA[12.58M..14.68M)
    {
        const size_t PS = 2097152;
        float* parts = bufA + 4194304;
        float* outb  = bufA + 12582912;
        conv3s2_v3<64, 128, 8, 4, false><<<dim3(4, 8, 2 * 4 * 4), blk, 0, stream>>>(
            bufA, e3w, e3b, st + 2 * 1024, st + 2 * 1024 + 512, parts, PS, 128, 256,
            nullptr);
        reduce_stats<4><<<dim3(2 * 128, 8), blk, 0, stream>>>(
            parts, PS, outb, acc + 3 * 1024, 64 * 128);
        in_stats_final<<<dim3(2), blk, 0, stream>>>(acc + 3 * 1024, st + 3 * 1024,
                                                    st + 3 * 1024 + 512, 2 * 128,
                                                    1.0f / (64 * 128));
    }

    // L4: 128->256, KS=4. in bufA[12.58M..14.68M); partials bufB[0..4.19M);
    // out -> bufB[4.19M..5.24M)
    {
        const size_t PS = 1048576;
        float* parts = bufB;
        float* outb  = bufB + 4194304;
        conv3s2_v3<128, 256, 8, 4, false><<<dim3(2, 4, 2 * 8 * 4), blk, 0, stream>>>(
            bufA + 12582912, e4w, e4b, st + 3 * 1024, st + 3 * 1024 + 512, parts, PS,
            64, 128, nullptr);
        reduce_stats<4><<<dim3(2 * 256, 8), blk, 0, stream>>>(
            parts, PS, outb, acc + 4 * 1024, 32 * 64);
        in_stats_final<<<dim3(2), blk, 0, stream>>>(acc + 4 * 1024, st + 4 * 1024,
                                                    st + 4 * 1024 + 512, 2 * 256,
                                                    1.0f / (32 * 64));
    }

    // D0: tconv 256->128, KS=4. in bufB[4.19M..5.24M); partials bufA[0..8.39M);
    // out -> bufB[0..2.1M)
    {
        const size_t PS = 2097152;
        tconv3_v2<256, 128, 16, 4><<<dim3(2, 4, 2 * 8 * 4), blk, 0, stream>>>(
            bufB + 4194304, d0w, d0b, st + 4 * 1024, st + 4 * 1024 + 512, bufA, PS,
            32, 64);
        reduce_stats<4><<<dim3(2 * 128, 8), blk, 0, stream>>>(
            bufA, PS, bufB, acc + 5 * 1024, 64 * 128);
        in_stats_final<<<dim3(2), blk, 0, stream>>>(acc + 5 * 1024, st + 5 * 1024,
                                                    st + 5 * 1024 + 512, 2 * 128,
                                                    1.0f / (64 * 128));
    }

    // D1: tconv 128->64, KS=2. in bufB[0..2.1M); partials bufA[0..8.39M);
    // out -> bufA[8.39M..12.58M)
    {
        const size_t PS = 4194304;
        tconv3_v2<128, 64, 16, 2><<<dim3(4, 8, 2 * 4 * 2), blk, 0, stream>>>(
            bufB, d1w, d1b, st + 5 * 1024, st + 5 * 1024 + 512, bufA, PS, 64, 128);
        reduce_stats<2><<<dim3(2 * 64, 8), blk, 0, stream>>>(
            bufA, PS, bufA + 8388608, acc + 6 * 1024, 128 * 256);
        in_stats_final<<<dim3(2), blk, 0, stream>>>(acc + 6 * 1024, st + 6 * 1024,
                                                    st + 6 * 1024 + 512, 2 * 64,
                                                    1.0f / (128 * 256));
    }

    // D2: tconv 64->32. in bufA[8.39M..12.58M) -> bufB[0..8.39M)
    tconv3_v2<64, 32, 16, 1><<<dim3(8, 16, 4), blk, 0, stream>>>(
        bufA + 8388608, d2w, d2b, st + 6 * 1024, st + 6 * 1024 + 512, bufB, 0,
        128, 256);
    STATS(bufB, 7, 32, 256 * 512);

    // D3: tconv 32->16. in bufB -> bufA (full)
    tconv3_v2<32, 16, 16, 1><<<dim3(16, 32, 2), blk, 0, stream>>>(
        bufB, d3w, d3b, st + 7 * 1024, st + 7 * 1024 + 512, bufA, 0, 256, 512);
    STATS(bufA, 8, 16, H * W);

    // D4: 7x7 reflect 16->3 + tanh. in bufA -> bufB[0..3.15M)
    conv7_lds<16, 3, 4, true, true><<<dim3(W / 32, H / 32, 2), blk, 0, stream>>>(
        bufA, d4w, d4b, st + 8 * 1024, st + 8 * 1024 + 512, bufB, H, W);

    // segment average pool
    seg_accum<<<dim3(256, 2), blk, 0, stream>>>(bufB, inst, seg, H * W);
    seg_means_k<<<dim3(1), blk, 0, stream>>>(seg, means);
    seg_scatter<<<dim3(512, 2), blk, 0, stream>>>(inst, means, outp, H * W);

#undef STATS
}

// Round 7
// 1075.458 us; speedup vs baseline: 1.5356x; 1.2191x over previous
//
#include <hip/hip_runtime.h>
#include <cstddef>

#define NUM_INST 32
#define EPS_IN 1e-5f

__device__ __forceinline__ int reflect_idx(int i, int n) {
    if (i < 0) i = -i;
    else if (i >= n) i = 2 * n - 2 - i;
    return i;
}

// ---------------- 7x7 reflect-pad conv, LDS-staged ---------------------------
template<int CIN, int COUT, int NCH, bool NORM, bool TANH>
__global__ void __launch_bounds__(256, 4)
conv7_lds(const float* __restrict__ x, const float* __restrict__ w,
          const float* __restrict__ bias,
          const float* __restrict__ mu, const float* __restrict__ rs,
          float* __restrict__ y, int H, int W)
{
    constexpr int COUTP = (COUT + 3) & ~3;
    __shared__ float wsm[CIN * 49 * COUTP];    // [ic][kh][kw][ocp]
    __shared__ float tile[NCH][38 * 39];
    __shared__ float smu[CIN], srs[CIN];
    const int tid = threadIdx.x;
    const int b = blockIdx.z;

    for (int idx = tid; idx < CIN * 49 * COUTP; idx += 256) {
        int ocp = idx % COUTP;
        int r   = idx / COUTP;
        wsm[idx] = (ocp < COUT) ? w[(size_t)ocp * CIN * 49 + r] : 0.f;
    }
    if (NORM && tid < CIN) { smu[tid] = mu[b * CIN + tid]; srs[tid] = rs[b * CIN + tid]; }

    const int oh_base = blockIdx.y * 32, ow_base = blockIdx.x * 32;
    const int ohl = tid >> 3, owl0 = (tid & 7) * 4;

    float acc[4][COUT];
#pragma unroll
    for (int o = 0; o < COUT; ++o) {
        float bv = bias[o];
#pragma unroll
        for (int j = 0; j < 4; ++j) acc[j][o] = bv;
    }

    for (int ic0 = 0; ic0 < CIN; ic0 += NCH) {
        __syncthreads();
        for (int idx = tid; idx < NCH * 1444; idx += 256) {
            int c = idx / 1444;
            int rr = idx % 1444;
            int r = rr / 38, col = rr % 38;
            int gy = reflect_idx(oh_base - 3 + r, H);
            int gx = reflect_idx(ow_base - 3 + col, W);
            float v = x[((size_t)(b * CIN + ic0 + c)) * H * W + (size_t)gy * W + gx];
            if (NORM) v = fmaxf((v - smu[ic0 + c]) * srs[ic0 + c], 0.f);
            tile[c][r * 39 + col] = v;
        }
        __syncthreads();
#pragma unroll
        for (int cc = 0; cc < NCH; ++cc) {
            const float* tp = &tile[cc][0];
            const float4* wp4 = (const float4*)&wsm[(ic0 + cc) * 49 * COUTP];
#pragma unroll
            for (int kh = 0; kh < 7; ++kh) {
                float rv[10];
#pragma unroll
                for (int i = 0; i < 10; ++i) rv[i] = tp[(ohl + kh) * 39 + owl0 + i];
#pragma unroll
                for (int kw = 0; kw < 7; ++kw) {
#pragma unroll
                    for (int o4 = 0; o4 < COUTP / 4; ++o4) {
                        float4 wv = wp4[(kh * 7 + kw) * (COUTP / 4) + o4];
#pragma unroll
                        for (int j = 0; j < 4; ++j) {
                            if (o4 * 4 + 0 < COUT) acc[j][o4 * 4 + 0] += rv[kw + j] * wv.x;
                            if (o4 * 4 + 1 < COUT) acc[j][o4 * 4 + 1] += rv[kw + j] * wv.y;
                            if (o4 * 4 + 2 < COUT) acc[j][o4 * 4 + 2] += rv[kw + j] * wv.z;
                            if (o4 * 4 + 3 < COUT) acc[j][o4 * 4 + 3] += rv[kw + j] * wv.w;
                        }
                    }
                }
            }
        }
    }

    const int oh = oh_base + ohl, ow0 = ow_base + owl0;
#pragma unroll
    for (int o = 0; o < COUT; ++o) {
        float4 st;
        st.x = acc[0][o]; st.y = acc[1][o]; st.z = acc[2][o]; st.w = acc[3][o];
        if (TANH) { st.x = tanhf(st.x); st.y = tanhf(st.y); st.z = tanhf(st.z); st.w = tanhf(st.w); }
        *(float4*)&y[(((size_t)b * COUT + o) * H + oh) * W + ow0] = st;
    }
}

// ---------------- 3x3 stride-2 conv (scalar loads, K-split) ------------------
// Proven zero-conflict structure (R4). KS>1: block handles CIN/KS channels,
// writes partial sums to y + ks*ystride; bias only at ks==0.
template<int CIN, int COUT, int OCPT, int KS, bool NORM>
__global__ void __launch_bounds__(256)
conv3_s2(const float* __restrict__ x, const float* __restrict__ w,
         const float* __restrict__ bias,
         const float* __restrict__ mu, const float* __restrict__ rs,
         float* __restrict__ y, size_t ystride, int Hin, int Win)
{
    const int Hout = Hin >> 1, Wout = Win >> 1;
    constexpr int CK = CIN / KS;
    __shared__ float wsm[CK * 9 * OCPT];     // [ic-local][tap][o]
    __shared__ float smu[CIN], srs[CIN];
    const int tid = threadIdx.x;
    const int NG = COUT / OCPT;
    const int z = blockIdx.z;
    const int ks = z % KS;
    const int ogb = z / KS;
    const int b = ogb / NG, g = ogb % NG;
    const int oc0 = g * OCPT;
    const int icbase = ks * CK;
    for (int idx = tid; idx < CK * 9 * OCPT; idx += 256) {
        int o = idx % OCPT;
        int r = idx / OCPT;                  // icl*9 + tap
        wsm[idx] = w[(size_t)(oc0 + o) * CIN * 9 + (size_t)icbase * 9 + r];
    }
    if (NORM && tid < CIN) { smu[tid] = mu[b * CIN + tid]; srs[tid] = rs[b * CIN + tid]; }
    __syncthreads();

    const int ow = blockIdx.x * 16 + (tid & 15);
    const int oh = blockIdx.y * 16 + (tid >> 4);

    float acc[OCPT];
#pragma unroll
    for (int o = 0; o < OCPT; ++o) acc[o] = (ks == 0) ? bias[oc0 + o] : 0.f;

    for (int icl = 0; icl < CK; ++icl) {
        const int ic = icbase + icl;
        const float* xp = x + ((size_t)(b * CIN + ic)) * Hin * Win;
        float m = NORM ? smu[ic] : 0.f;
        float rr = NORM ? srs[ic] : 0.f;
#pragma unroll
        for (int kh = 0; kh < 3; ++kh) {
            int ih = 2 * oh + kh - 1;
            if (ih < 0 || ih >= Hin) continue;
#pragma unroll
            for (int kw = 0; kw < 3; ++kw) {
                int iw = 2 * ow + kw - 1;
                if (iw < 0 || iw >= Win) continue;
                float v = xp[(size_t)ih * Win + iw];
                if (NORM) v = fmaxf((v - m) * rr, 0.f);
                const float* wp = &wsm[(icl * 9 + kh * 3 + kw) * OCPT];
#pragma unroll
                for (int o = 0; o < OCPT; ++o) acc[o] += wp[o] * v;
            }
        }
    }
    float* yb = y + (size_t)ks * ystride;
    float* yp = yb + (((size_t)b * COUT + oc0) * Hout + oh) * Wout + ow;
#pragma unroll
    for (int o = 0; o < OCPT; ++o) yp[(size_t)o * Hout * Wout] = acc[o];
}

// ---------------- 3x3 stride-2 transposed conv (LDS + reg tiles, K-split) ----
template<int CIN, int COUT, int ICB, int KS>
__global__ void __launch_bounds__(256)
tconv3_v2(const float* __restrict__ x, const float* __restrict__ w,
          const float* __restrict__ bias,
          const float* __restrict__ mu, const float* __restrict__ rs,
          float* __restrict__ y, size_t ystride, int Hin, int Win)
{
    constexpr int OCB = 16;
    constexpr int NOG = COUT / OCB;
    constexpr int CK = CIN / KS;
    const int z = blockIdx.z;
    const int ks = z % KS;
    const int ogb = z / KS;
    const int b = ogb / NOG;
    const int ocb = (ogb % NOG) * OCB;
    const int r0 = blockIdx.y * 8, c0 = blockIdx.x * 32;
    const int Hout = Hin * 2, Wout = Win * 2;

    __shared__ float xt[ICB][9 * 36];
    __shared__ float wt[ICB][9][OCB];
    __shared__ float smu[CIN], srs[CIN];

    const int tid = threadIdx.x;
    if (tid < CIN) { smu[tid] = mu[b * CIN + tid]; srs[tid] = rs[b * CIN + tid]; }

    const int tid_s = tid & 63;
    const int og = tid >> 6;
    const int sr = tid_s >> 3;
    const int sc4 = (tid_s & 7) * 4;

    float acc[4][4][4];
#pragma unroll
    for (int o = 0; o < 4; ++o) {
        float bv = (ks == 0) ? bias[ocb + og * 4 + o] : 0.f;
#pragma unroll
        for (int pr = 0; pr < 4; ++pr)
#pragma unroll
            for (int p = 0; p < 4; ++p) acc[pr][o][p] = bv;
    }

    for (int ic0 = ks * CK; ic0 < (ks + 1) * CK; ic0 += ICB) {
        __syncthreads();
        for (int idx = tid; idx < ICB * 9 * 33; idx += 256) {
            int c  = idx / (9 * 33);
            int rr = idx % (9 * 33);
            int r  = rr / 33, col = rr % 33;
            int gr = r0 + r, gc = c0 + col;
            int ic = ic0 + c;
            float v = 0.f;
            if (gr < Hin && gc < Win) {
                v = x[((size_t)(b * CIN + ic)) * Hin * Win + (size_t)gr * Win + gc];
                v = fmaxf((v - smu[ic]) * srs[ic], 0.f);
            }
            xt[c][r * 36 + col] = v;
        }
        for (int idx = tid; idx < ICB * 9 * OCB; idx += 256) {
            int oc  = idx & (OCB - 1);
            int tap = (idx >> 4) % 9;
            int c   = idx / (9 * OCB);
            wt[c][tap][oc] = w[(size_t)(ocb + oc) * CIN * 9 + (size_t)(ic0 + c) * 9 + tap];
        }
        __syncthreads();

#pragma unroll 4
        for (int c = 0; c < ICB; ++c) {
            const float* xr = &xt[c][sr * 36 + sc4];
            float x0[5], x1[5];
            {
                float4 a = *(const float4*)xr;
                x0[0] = a.x; x0[1] = a.y; x0[2] = a.z; x0[3] = a.w; x0[4] = xr[4];
                float4 bq = *(const float4*)(xr + 36);
                x1[0] = bq.x; x1[1] = bq.y; x1[2] = bq.z; x1[3] = bq.w; x1[4] = xr[40];
            }
            const float* wp = &wt[c][0][og * 4];
#define TAPFMA(TAP, PAR, XV, SH)                                                   \
            {                                                                      \
                float4 wq = *(const float4*)(wp + (TAP) * OCB);                    \
                float wv[4] = {wq.x, wq.y, wq.z, wq.w};                            \
                _Pragma("unroll")                                                  \
                for (int o = 0; o < 4; ++o)                                        \
                    _Pragma("unroll")                                              \
                    for (int p = 0; p < 4; ++p)                                    \
                        acc[PAR][o][p] += wv[o] * XV[p + SH];                      \
            }
            TAPFMA(4, 0, x0, 0)
            TAPFMA(5, 1, x0, 0)
            TAPFMA(3, 1, x0, 1)
            TAPFMA(7, 2, x0, 0)
            TAPFMA(1, 2, x1, 0)
            TAPFMA(8, 3, x0, 0)
            TAPFMA(6, 3, x0, 1)
            TAPFMA(2, 3, x1, 0)
            TAPFMA(0, 3, x1, 1)
#undef TAPFMA
        }
    }

    float* yb = y + (size_t)ks * ystride;
    const int gr = r0 + sr, gc = c0 + sc4;
#pragma unroll
    for (int o = 0; o < 4; ++o) {
        int oc = ocb + og * 4 + o;
        float* yp = yb + (((size_t)(b * COUT + oc)) * Hout + 2 * gr) * Wout + 2 * gc;
        float4 e0, e1, d0, d1;
        e0.x = acc[0][o][0]; e0.y = acc[1][o][0]; e0.z = acc[0][o][1]; e0.w = acc[1][o][1];
        e1.x = acc[0][o][2]; e1.y = acc[1][o][2]; e1.z = acc[0][o][3]; e1.w = acc[1][o][3];
        d0.x = acc[2][o][0]; d0.y = acc[3][o][0]; d0.z = acc[2][o][1]; d0.w = acc[3][o][1];
        d1.x = acc[2][o][2]; d1.y = acc[3][o][2]; d1.z = acc[2][o][3]; d1.w = acc[3][o][3];
        *(float4*)yp = e0;
        *(float4*)(yp + 4) = e1;
        *(float4*)(yp + Wout) = d0;
        *(float4*)(yp + Wout + 4) = d1;
    }
}

// ---------------- reduce K-split partials + fused IN stats -------------------
template<int KS>
__global__ void __launch_bounds__(256)
reduce_stats(const float* __restrict__ parts, size_t pstride,
             float* __restrict__ out, float* __restrict__ acc, int HW)
{
    const int bc = blockIdx.x;
    const int chunk = HW / gridDim.y;
    const size_t base = (size_t)bc * HW + (size_t)blockIdx.y * chunk;
    float s = 0.f, ss = 0.f;
    const int n4 = chunk >> 2;
    for (int i = threadIdx.x; i < n4; i += 256) {
        float4 v = ((const float4*)(parts + base))[i];
#pragma unroll
        for (int k = 1; k < KS; ++k) {
            float4 u = ((const float4*)(parts + (size_t)k * pstride + base))[i];
            v.x += u.x; v.y += u.y; v.z += u.z; v.w += u.w;
        }
        ((float4*)(out + base))[i] = v;
        s += v.x + v.y + v.z + v.w;
        ss += v.x * v.x + v.y * v.y + v.z * v.z + v.w * v.w;
    }
#pragma unroll
    for (int off = 32; off; off >>= 1) {
        s += __shfl_down(s, off);
        ss += __shfl_down(ss, off);
    }
    __shared__ float rbuf[8];
    const int wid = threadIdx.x >> 6;
    if ((threadIdx.x & 63) == 0) { rbuf[wid] = s; rbuf[4 + wid] = ss; }
    __syncthreads();
    if (threadIdx.x == 0) {
        s = rbuf[0] + rbuf[1] + rbuf[2] + rbuf[3];
        ss = rbuf[4] + rbuf[5] + rbuf[6] + rbuf[7];
        atomicAdd(&acc[bc], s);
        atomicAdd(&acc[512 + bc], ss);
    }
}

// ---------------- instance-norm stats: partial (atomic) + finalize -----------
__global__ void __launch_bounds__(256)
in_stats_partial(const float* __restrict__ y, float* __restrict__ acc, int HW)
{
    const int bc = blockIdx.x;
    const int chunk = HW / gridDim.y;
    const float* p = y + (size_t)bc * HW + (size_t)blockIdx.y * chunk;
    float s = 0.f, ss = 0.f;
    const float4* p4 = (const float4*)p;
    const int n4 = chunk >> 2;
    for (int i = threadIdx.x; i < n4; i += 256) {
        float4 v = p4[i];
        s += v.x + v.y + v.z + v.w;
        ss += v.x * v.x + v.y * v.y + v.z * v.z + v.w * v.w;
    }
#pragma unroll
    for (int off = 32; off; off >>= 1) {
        s += __shfl_down(s, off);
        ss += __shfl_down(ss, off);
    }
    __shared__ float rbuf[8];
    const int wid = threadIdx.x >> 6;
    if ((threadIdx.x & 63) == 0) { rbuf[wid] = s; rbuf[4 + wid] = ss; }
    __syncthreads();
    if (threadIdx.x == 0) {
        s = rbuf[0] + rbuf[1] + rbuf[2] + rbuf[3];
        ss = rbuf[4] + rbuf[5] + rbuf[6] + rbuf[7];
        atomicAdd(&acc[bc], s);
        atomicAdd(&acc[512 + bc], ss);
    }
}

__global__ void in_stats_final(const float* __restrict__ acc,
                               float* __restrict__ mu, float* __restrict__ rs,
                               int BC, float invHW)
{
    int i = blockIdx.x * 256 + threadIdx.x;
    if (i < BC) {
        float m = acc[i] * invHW;
        float var = fmaxf(acc[512 + i] * invHW - m * m, 0.f);
        mu[i] = m;
        rs[i] = rsqrtf(var + EPS_IN);
    }
}

// ---------------- segment average pooling ------------------------------------
__global__ void zero_ws_k(float* __restrict__ p, int n)
{
    int i = blockIdx.x * 256 + threadIdx.x;
    if (i < n) p[i] = 0.f;
}

__global__ void __launch_bounds__(256)
seg_accum(const float* __restrict__ yT, const int* __restrict__ inst,
          float* __restrict__ seg, int HW)
{
    const int b = blockIdx.y;
    __shared__ float ls[NUM_INST * 4];
    if (threadIdx.x < NUM_INST * 4) ls[threadIdx.x] = 0.f;
    __syncthreads();
    const float* p0 = yT + (size_t)b * 3 * HW;
    const int* ip = inst + (size_t)b * HW;
    for (int i = blockIdx.x * 256 + threadIdx.x; i < HW; i += gridDim.x * 256) {
        int id = ip[i];
        atomicAdd(&ls[id * 4 + 0], p0[i]);
        atomicAdd(&ls[id * 4 + 1], p0[HW + i]);
        atomicAdd(&ls[id * 4 + 2], p0[2 * (size_t)HW + i]);
        atomicAdd(&ls[id * 4 + 3], 1.f);
    }
    __syncthreads();
    if (threadIdx.x < NUM_INST * 4)
        atomicAdd(&seg[b * NUM_INST * 4 + threadIdx.x], ls[threadIdx.x]);
}

__global__ void seg_means_k(const float* __restrict__ seg, float* __restrict__ means)
{
    int i = threadIdx.x;
    if (i < 2 * NUM_INST * 3) {
        int bi = i / 3, c = i % 3;
        float cnt = seg[bi * 4 + 3];
        means[i] = seg[bi * 4 + c] / fmaxf(cnt, 1.f);
    }
}

__global__ void __launch_bounds__(256)
seg_scatter(const int* __restrict__ inst, const float* __restrict__ means,
            float* __restrict__ out, int HW)
{
    const int b = blockIdx.y;
    for (int i = blockIdx.x * 256 + threadIdx.x; i < HW; i += gridDim.x * 256) {
        int id = inst[(size_t)b * HW + i];
        const float* m = &means[(b * NUM_INST + id) * 3];
        out[((size_t)b * 3 + 0) * HW + i] = m[0];
        out[((size_t)b * 3 + 1) * HW + i] = m[1];
        out[((size_t)b * 3 + 2) * HW + i] = m[2];
    }
}

// ---------------- driver -----------------------------------------------------
extern "C" void kernel_launch(void* const* d_in, const int* in_sizes, int n_in,
                              void* d_out, int out_size, void* d_ws, size_t ws_size,
                              hipStream_t stream)
{
    const float* x_in = (const float*)d_in[0];
    const int* inst = (const int*)d_in[1];
    const float* e0w = (const float*)d_in[2];  const float* e0b = (const float*)d_in[3];
    const float* e1w = (const float*)d_in[4];  const float* e1b = (const float*)d_in[5];
    const float* e2w = (const float*)d_in[6];  const float* e2b = (const float*)d_in[7];
    const float* e3w = (const float*)d_in[8];  const float* e3b = (const float*)d_in[9];
    const float* e4w = (const float*)d_in[10]; const float* e4b = (const float*)d_in[11];
    const float* d0w = (const float*)d_in[12]; const float* d0b = (const float*)d_in[13];
    const float* d1w = (const float*)d_in[14]; const float* d1b = (const float*)d_in[15];
    const float* d2w = (const float*)d_in[16]; const float* d2b = (const float*)d_in[17];
    const float* d3w = (const float*)d_in[18]; const float* d3b = (const float*)d_in[19];
    const float* d4w = (const float*)d_in[20]; const float* d4b = (const float*)d_in[21];
    float* outp = (float*)d_out;

    float* bufA = (float*)d_ws;                       // 16777216 floats
    float* bufB = bufA + 16777216;                    // 8388608 floats
    float* st   = bufB + 8388608;                     // 9 layers x 1024 (mu|rs)
    float* acc  = st + 9 * 1024;                      // 9 layers x 1024 (sum|ss)
    float* seg  = acc + 9 * 1024;                     // 2*32*4
    float* means = seg + 2 * NUM_INST * 4;            // 2*32*3

    const dim3 blk(256);
    const int H = 512, W = 1024;

    {
        int nz = 9 * 1024 + 2 * NUM_INST * 4;
        zero_ws_k<<<dim3((nz + 255) / 256), blk, 0, stream>>>(acc, nz);
    }

#define STATS(buf, L, C, HWv)                                                        \
    in_stats_partial<<<dim3(2 * (C), 8), blk, 0, stream>>>((buf), acc + (L) * 1024, (HWv)); \
    in_stats_final<<<dim3(2), blk, 0, stream>>>(acc + (L) * 1024, st + (L) * 1024,          \
                                                st + (L) * 1024 + 512, 2 * (C),             \
                                                1.0f / (HWv));

    // L0: e0 7x7 reflect, 3->16 -> bufA
    conv7_lds<3, 16, 3, false, false><<<dim3(W / 32, H / 32, 2), blk, 0, stream>>>(
        x_in, e0w, e0b, nullptr, nullptr, bufA, H, W);
    STATS(bufA, 0, 16, H * W);

    // L1: 16->32 -> bufB
    conv3_s2<16, 32, 8, 1, true><<<dim3(32, 16, 2 * 4), blk, 0, stream>>>(
        bufA, e1w, e1b, st + 0 * 1024, st + 0 * 1024 + 512, bufB, 0, 512, 1024);
    STATS(bufB, 1, 32, 256 * 512);

    // L2: 32->64 -> bufA[0..4.2M)
    conv3_s2<32, 64, 8, 1, true><<<dim3(16, 8, 2 * 8), blk, 0, stream>>>(
        bufB, e2w, e2b, st + 1 * 1024, st + 1 * 1024 + 512, bufA, 0, 256, 512);
    STATS(bufA, 2, 64, 128 * 256);

    // L3: 64->128, KS=2. in bufA[0..4.2M); partials bufB[2.1M..6.3M);
    // out -> bufB[0..2.1M)
    {
        const size_t PS = 2097152;                    // 2*128*64*128
        float* parts = bufB + 2097152;
        conv3_s2<64, 128, 8, 2, true><<<dim3(8, 4, 2 * 16 * 2), blk, 0, stream>>>(
            bufA, e3w, e3b, st + 2 * 1024, st + 2 * 1024 + 512, parts, PS, 128, 256);
        reduce_stats<2><<<dim3(2 * 128, 8), blk, 0, stream>>>(
            parts, PS, bufB, acc + 3 * 1024, 64 * 128);
        in_stats_final<<<dim3(2), blk, 0, stream>>>(acc + 3 * 1024, st + 3 * 1024,
                                                    st + 3 * 1024 + 512, 2 * 128,
                                                    1.0f / (64 * 128));
    }

    // L4: 128->256, KS=4. in bufB[0..2.1M); partials bufA[1M..5M);
    // out -> bufA[0..1M)
    {
        const size_t PS = 1048576;                    // 2*256*32*64
        float* parts = bufA + 1048576;
        conv3_s2<128, 256, 8, 4, true><<<dim3(4, 2, 2 * 32 * 4), blk, 0, stream>>>(
            bufB, e4w, e4b, st + 3 * 1024, st + 3 * 1024 + 512, parts, PS, 64, 128);
        reduce_stats<4><<<dim3(2 * 256, 8), blk, 0, stream>>>(
            parts, PS, bufA, acc + 4 * 1024, 32 * 64);
        in_stats_final<<<dim3(2), blk, 0, stream>>>(acc + 4 * 1024, st + 4 * 1024,
                                                    st + 4 * 1024 + 512, 2 * 256,
                                                    1.0f / (32 * 64));
    }

    // D0: tconv 256->128, KS=4. in bufA[0..1M); partials bufA[2M..10.4M);
    // out -> bufB[0..2.1M)
    {
        const size_t PS = 2097152;
        float* parts = bufA + 2097152;
        tconv3_v2<256, 128, 16, 4><<<dim3(2, 4, 2 * 8 * 4), blk, 0, stream>>>(
            bufA, d0w, d0b, st + 4 * 1024, st + 4 * 1024 + 512, parts, PS, 32, 64);
        reduce_stats<4><<<dim3(2 * 128, 8), blk, 0, stream>>>(
            parts, PS, bufB, acc + 5 * 1024, 64 * 128);
        in_stats_final<<<dim3(2), blk, 0, stream>>>(acc + 5 * 1024, st + 5 * 1024,
                                                    st + 5 * 1024 + 512, 2 * 128,
                                                    1.0f / (64 * 128));
    }

    // D1: tconv 128->64, KS=2. in bufB[0..2.1M); partials bufA[8.39M..16.78M);
    // out -> bufA[0..4.2M)
    {
        const size_t PS = 4194304;
        float* parts = bufA + 8388608;
        tconv3_v2<128, 64, 16, 2><<<dim3(4, 8, 2 * 4 * 2), blk, 0, stream>>>(
            bufB, d1w, d1b, st + 5 * 1024, st + 5 * 1024 + 512, parts, PS, 64, 128);
        reduce_stats<2><<<dim3(2 * 64, 8), blk, 0, stream>>>(
            parts, PS, bufA, acc + 6 * 1024, 128 * 256);
        in_stats_final<<<dim3(2), blk, 0, stream>>>(acc + 6 * 1024, st + 6 * 1024,
                                                    st + 6 * 1024 + 512, 2 * 64,
                                                    1.0f / (128 * 256));
    }

    // D2: tconv 64->32. in bufA[0..4.2M) -> bufB[0..8.39M)
    tconv3_v2<64, 32, 16, 1><<<dim3(8, 16, 2 * 2), blk, 0, stream>>>(
        bufA, d2w, d2b, st + 6 * 1024, st + 6 * 1024 + 512, bufB, 0, 128, 256);
    STATS(bufB, 7, 32, 256 * 512);

    // D3: tconv 32->16. in bufB -> bufA (full)
    tconv3_v2<32, 16, 16, 1><<<dim3(16, 32, 2), blk, 0, stream>>>(
        bufB, d3w, d3b, st + 7 * 1024, st + 7 * 1024 + 512, bufA, 0, 256, 512);
    STATS(bufA, 8, 16, H * W);

    // D4: 7x7 reflect 16->3 + tanh. in bufA -> bufB
    conv7_lds<16, 3, 4, true, true><<<dim3(W / 32, H / 32, 2), blk, 0, stream>>>(
        bufA, d4w, d4b, st + 8 * 1024, st + 8 * 1024 + 512, bufB, H, W);

    // segment average pool
    seg_accum<<<dim3(256, 2), blk, 0, stream>>>(bufB, inst, seg, H * W);
    seg_means_k<<<dim3(1), blk, 0, stream>>>(seg, means);
    seg_scatter<<<dim3(512, 2), blk, 0, stream>>>(inst, means, outp, H * W);

#undef STATS
}